// Round 10
// baseline (245.299 us; speedup 1.0000x reference)
//
#include <hip/hip_runtime.h>
#include <hip/hip_bf16.h>

typedef unsigned short u16;
typedef unsigned int u32;
typedef __attribute__((ext_vector_type(8))) short bf16x8;  // 8 bf16 (4 VGPRs)
typedef __attribute__((ext_vector_type(4))) short bf16x4;  // 4 bf16 (2 VGPRs)
typedef __attribute__((ext_vector_type(4))) float f32x4;

#define DEVI __device__ __forceinline__

DEVI u16 f2bf(float f) {
  union { float f; unsigned int u; } v; v.f = f;
  unsigned int u = v.u;
  unsigned int r = (u + 0x7fffu + ((u >> 16) & 1u)) >> 16;  // RNE
  return (u16)r;
}

DEVI float bf2f(u16 b) {
  union { unsigned int u; float f; } v; v.u = ((unsigned int)b) << 16;
  return v.f;
}

DEVI float fexp2(float x) {
#if __has_builtin(__builtin_amdgcn_exp2f)
  return __builtin_amdgcn_exp2f(x);
#else
  return exp2f(x);
#endif
}

// pack two fp32 -> two bf16 (round +half) in one u32: b -> low16, a -> high16
DEVI u32 pkbf(float a, float b) {
  union { float f; u32 u; } ua, ub;
  ua.f = a; ub.f = b;
  return __builtin_amdgcn_perm(ua.u + 0x8000u, ub.u + 0x8000u, 0x07060302u);
}

// async global->LDS, 16B per lane; LDS dest = uniform base + lane*16
DEVI void lds_cp16(u16* lds, const u16* g) {
  __builtin_amdgcn_global_load_lds(
      (const __attribute__((address_space(1))) u32*)g,
      (__attribute__((address_space(3))) u32*)lds, 16, 0, 0);
}

DEVI f32x4 mfma16x16x16_bf16(bf16x4 a, bf16x4 b, f32x4 c) {
#if __has_builtin(__builtin_amdgcn_mfma_f32_16x16x16bf16_1k)
  return __builtin_amdgcn_mfma_f32_16x16x16bf16_1k(a, b, c, 0, 0, 0);
#else
  f32x4 d;
  asm volatile("v_mfma_f32_16x16x16_bf16 %0, %1, %2, %3"
               : "=v"(d) : "v"(a), "v"(b), "v"(c));
  return d;
#endif
}

// ---------------- fp32 -> bf16 conversion (x, w_in, w_out merged) ----------------
__global__ __launch_bounds__(256) void cvt_all(
    const float4* __restrict__ x, const float4* __restrict__ wi,
    const float4* __restrict__ wo, u16* __restrict__ xb,
    u16* __restrict__ wib, u16* __restrict__ wob) {
  int i = blockIdx.x * 256 + threadIdx.x;
  const float4* src; u16* dst; int off;
  if (i < 524288)      { src = x;  dst = xb;  off = i; }
  else if (i < 720896) { src = wi; dst = wib; off = i - 524288; }
  else                 { src = wo; dst = wob; off = i - 720896; }
  float4 f = src[off];
  ushort4 o;
  o.x = f2bf(f.x); o.y = f2bf(f.y); o.z = f2bf(f.z); o.w = f2bf(f.w);
  ((ushort4*)dst)[off] = o;
}

// ---------------- in_proj GEMM: qvk = x @ w_in^T + b_in (R3-proven config) ----------------
// Q is PRE-SCALED by (1/sqrt(64))*log2(e) so attention scores come out in
// exp2 domain with no per-score multiply.
__global__ __launch_bounds__(256) void inproj_gemm(
    const u16* __restrict__ xb, const u16* __restrict__ wb,
    const float* __restrict__ bin,
    u16* __restrict__ Qb, u16* __restrict__ Kb, u16* __restrict__ Vt) {
  const int K = 512;
  const float SCL = 0.180336878f;  // (1/sqrt(64)) * log2(e)
  __shared__ u16 At[2][128 * 32];
  __shared__ u16 Bt[2][128 * 32];
  int tid = threadIdx.x;
  int w = tid >> 6, lane = tid & 63;
  int ql = lane & 15, quad = lane >> 4;
  int wr = w >> 1, wc = w & 1;
  int mtile = blockIdx.x * 128, ntile = blockIdx.y * 128;

  int r4 = lane >> 2, c4 = lane & 3;
  int swz4 = c4 ^ (r4 & 3);

  const u16* ag0 = xb + (size_t)(mtile + w * 32 + r4) * K + swz4 * 8;
  const u16* bg0 = wb + (size_t)(ntile + w * 32 + r4) * K + swz4 * 8;

  f32x4 acc[4][4];
#pragma unroll
  for (int t = 0; t < 4; ++t)
#pragma unroll
    for (int u = 0; u < 4; ++u) acc[t][u] = (f32x4){0, 0, 0, 0};

  lds_cp16(&At[0][w * 1024], ag0);
  lds_cp16(&At[0][w * 1024 + 512], ag0 + 16 * K);
  lds_cp16(&Bt[0][w * 1024], bg0);
  lds_cp16(&Bt[0][w * 1024 + 512], bg0 + 16 * K);

  int cb = ql & 3;
  for (int kk = 0; kk < 16; ++kk) {
    int cur = kk & 1;
    __syncthreads();
    if (kk < 15) {
      int k0 = (kk + 1) * 32;
      lds_cp16(&At[cur ^ 1][w * 1024], ag0 + k0);
      lds_cp16(&At[cur ^ 1][w * 1024 + 512], ag0 + 16 * K + k0);
      lds_cp16(&Bt[cur ^ 1][w * 1024], bg0 + k0);
      lds_cp16(&Bt[cur ^ 1][w * 1024 + 512], bg0 + 16 * K + k0);
    }
    bf16x8 af[4], bf[4];
#pragma unroll
    for (int t = 0; t < 4; ++t) {
      int row = wr * 64 + t * 16 + ql;
      af[t] = *(const bf16x8*)(&At[cur][row * 32 + ((quad ^ cb) * 8)]);
    }
#pragma unroll
    for (int u = 0; u < 4; ++u) {
      int row = wc * 64 + u * 16 + ql;
      bf[u] = *(const bf16x8*)(&Bt[cur][row * 32 + ((quad ^ cb) * 8)]);
    }
#pragma unroll
    for (int t = 0; t < 4; ++t)
#pragma unroll
      for (int u = 0; u < 4; ++u)
        acc[t][u] = __builtin_amdgcn_mfma_f32_16x16x32_bf16(af[t], bf[u], acc[t][u], 0, 0, 0);
  }

#pragma unroll
  for (int u = 0; u < 4; ++u) {
    int n = ntile + wc * 64 + u * 16 + ql;
    float bias = bin[n];
    int chunk = n >> 9;       // 0=q, 1=v, 2=k
    int nc = n & 511;
    int h = nc >> 6, d = nc & 63;
#pragma unroll
    for (int t = 0; t < 4; ++t)
#pragma unroll
      for (int r = 0; r < 4; ++r) {
        int m = mtile + wr * 64 + t * 16 + quad * 4 + r;
        int b = m >> 11, s = m & 2047;
        float v = acc[t][u][r] + bias;
        int bh = b * 8 + h;
        if (chunk == 0)      Qb[((size_t)bh * 2048 + s) * 64 + d] = f2bf(v * SCL);
        else if (chunk == 2) Kb[((size_t)bh * 2048 + s) * 64 + d] = f2bf(v);
        else                 Vt[((size_t)bh * 64 + d) * 2048 + s] = f2bf(v);
      }
  }
}

// ---------------- flash attention (causal): wave-per-key-slice, A/B phases ----------------
// Pair j = tiles A=j, B=31-j; 33 items split 11/11/11 across 3 chunk-WGs
// (grid 16x3x16). Wave w owns keys [16w,16w+16) of every staged 64-key block
// and computes partial O^T over ALL 64 q-rows of the current tile (Q in
// registers). 4x fewer LDS reads/wave than q-split; 16 independent PV accums.
// Cross-wave O merge (rotating-quarter, wave-UNIFORM branch select -- NO
// dynamic register indexing, that spilled in R9) at each phase flush.
// Fixed-max softmax (exp2 domain, Q pre-scaled).
__global__ __launch_bounds__(256, 3) void attn_kernel(
    const u16* __restrict__ Qb, const u16* __restrict__ Kb,
    const u16* __restrict__ Vt, u16* __restrict__ Pp, float* __restrict__ Ml) {
  const int S = 2048;
  __shared__ u16 Kt[2][4096];      // [buf][64 keys x 64 dh], 16B chunks swizzled
  __shared__ u16 Vl[2][4096];      // [buf][64 dh x 64 keys], swizzled
  __shared__ float Mg[64 * 66];    // O merge buffer [q][d], stride 66
  __shared__ float Lg[4][64];      // per-wave l partials [w][q]
  int tid = threadIdx.x;
  int w = tid >> 6, lane = tid & 63;
  int ql = lane & 15, quad = lane >> 4;
  int j = blockIdx.x, c = blockIdx.y, bh = blockIdx.z;
  int tileA = j, tileB = 31 - j;
  const u16* Qh = Qb + (size_t)bh * S * 64;
  const u16* Kh = Kb + (size_t)bh * S * 64;
  const u16* Vh = Vt + (size_t)bh * 64 * S;
  int r8 = lane >> 3, c8 = lane & 7;
  int swz = c8 ^ r8;
  int cb = ql & 7;

  int rsw = j + 1 - c * 11;        // rounds < rsw are tile A
  if (rsw < 0) rsw = 0;
  if (rsw > 11) rsw = 11;

  bf16x8 qf0, qf1, qf2, qf3, qg0, qg1, qg2, qg3;  // Q frags (scalars, no array)
  f32x4 o[4][4];                   // O^T accum [d-tile][q-tile] (all const-indexed)
  float l[4];

  auto loadQ = [&](int tile) {
    const u16* qp = Qh + (size_t)(tile * 64 + ql) * 64 + quad * 8;
    qf0 = *(const bf16x8*)(qp);
    qg0 = *(const bf16x8*)(qp + 32);
    qf1 = *(const bf16x8*)(qp + 1024);
    qg1 = *(const bf16x8*)(qp + 1024 + 32);
    qf2 = *(const bf16x8*)(qp + 2048);
    qg2 = *(const bf16x8*)(qp + 2048 + 32);
    qf3 = *(const bf16x8*)(qp + 3072);
    qg3 = *(const bf16x8*)(qp + 3072 + 32);
  };
  auto zeroAcc = [&]() {
#pragma unroll
    for (int dt = 0; dt < 4; ++dt)
#pragma unroll
      for (int qt = 0; qt < 4; ++qt) o[dt][qt] = (f32x4){0, 0, 0, 0};
#pragma unroll
    for (int qt = 0; qt < 4; ++qt) l[qt] = 0.0f;
  };
  auto stage = [&](int buf, int kbase) {
    const u16* kg = Kh + (size_t)(kbase + w * 16 + r8) * 64 + swz * 8;
    lds_cp16(&Kt[buf][w * 1024], kg);
    lds_cp16(&Kt[buf][w * 1024 + 512], kg + 8 * 64);
    const u16* vg = Vh + (size_t)(w * 16 + r8) * S + kbase + swz * 8;
    lds_cp16(&Vl[buf][w * 1024], vg);
    lds_cp16(&Vl[buf][w * 1024 + 512], vg + 8 * S);
  };
  auto process = [&](int cur, int diag) {
    // S^T = K_slice x Q : A = K rows (w*16+ql), B = Q fragments
    const u16* kr = &Kt[cur][(w * 16 + ql) * 64];
    bf16x8 kf0 = *(const bf16x8*)(kr + ((quad ^ cb) * 8));          // dh 0..31
    bf16x8 kf1 = *(const bf16x8*)(kr + (((quad + 4) ^ cb) * 8));    // dh 32..63
    f32x4 s[4];
    {
      f32x4 t0 = {0,0,0,0}, t1 = {0,0,0,0}, t2 = {0,0,0,0}, t3 = {0,0,0,0};
      t0 = __builtin_amdgcn_mfma_f32_16x16x32_bf16(kf0, qf0, t0, 0, 0, 0);
      t1 = __builtin_amdgcn_mfma_f32_16x16x32_bf16(kf0, qf1, t1, 0, 0, 0);
      t2 = __builtin_amdgcn_mfma_f32_16x16x32_bf16(kf0, qf2, t2, 0, 0, 0);
      t3 = __builtin_amdgcn_mfma_f32_16x16x32_bf16(kf0, qf3, t3, 0, 0, 0);
      t0 = __builtin_amdgcn_mfma_f32_16x16x32_bf16(kf1, qg0, t0, 0, 0, 0);
      t1 = __builtin_amdgcn_mfma_f32_16x16x32_bf16(kf1, qg1, t1, 0, 0, 0);
      t2 = __builtin_amdgcn_mfma_f32_16x16x32_bf16(kf1, qg2, t2, 0, 0, 0);
      t3 = __builtin_amdgcn_mfma_f32_16x16x32_bf16(kf1, qg3, t3, 0, 0, 0);
      s[0] = t0; s[1] = t1; s[2] = t2; s[3] = t3;
    }
    float e[4][4];
#pragma unroll
    for (int qt = 0; qt < 4; ++qt)
#pragma unroll
      for (int r = 0; r < 4; ++r) {
        float v = s[qt][r];
        if (diag) {
          int key = w * 16 + quad * 4 + r;   // relative to block
          int qq = qt * 16 + ql;             // relative to tile
          if (key > qq) v = -3.0e38f;        // exp2 -> 0
        }
        e[qt][r] = fexp2(v);
      }
#pragma unroll
    for (int qt = 0; qt < 4; ++qt)
      l[qt] += (e[qt][0] + e[qt][1]) + (e[qt][2] + e[qt][3]);
    bf16x4 p[4];
#pragma unroll
    for (int qt = 0; qt < 4; ++qt) {
      union { bf16x4 v; u32 u[2]; } pk;
      pk.u[0] = pkbf(e[qt][1], e[qt][0]);
      pk.u[1] = pkbf(e[qt][3], e[qt][2]);
      p[qt] = pk.v;
    }
    // O^T += V^T_slice x P^T : 16 independent accumulators, const-indexed
#pragma unroll
    for (int dt = 0; dt < 4; ++dt) {
      const u16* vr = &Vl[cur][(dt * 16 + ql) * 64];
      bf16x4 vf = *(const bf16x4*)(vr + (((w * 2 + (quad >> 1)) ^ cb) * 8 + (quad & 1) * 4));
      o[dt][0] = mfma16x16x16_bf16(vf, p[0], o[dt][0]);
      o[dt][1] = mfma16x16x16_bf16(vf, p[1], o[dt][1]);
      o[dt][2] = mfma16x16x16_bf16(vf, p[2], o[dt][2]);
      o[dt][3] = mfma16x16x16_bf16(vf, p[3], o[dt][3]);
    }
  };
  auto flush = [&](int t01) {
    // l: reduce across quads
    float lv[4];
#pragma unroll
    for (int qt = 0; qt < 4; ++qt) {
      float x = l[qt];
      x += __shfl_xor(x, 16);
      x += __shfl_xor(x, 32);
      lv[qt] = x;
    }
    if (quad == 0) {
#pragma unroll
      for (int qt = 0; qt < 4; ++qt) Lg[w][qt * 16 + ql] = lv[qt];
    }
    // O: rotating-quarter accumulate into Mg. dt is wave-uniform; select the
    // accumulator with a UNIFORM branch (compile-time indices only -> no spill).
#pragma unroll
    for (int st = 0; st < 4; ++st) {
      __syncthreads();
      int dt = (w + st) & 3;
#pragma unroll
      for (int qt = 0; qt < 4; ++qt) {
        f32x4 val;
        if (dt == 0)      val = o[0][qt];
        else if (dt == 1) val = o[1][qt];
        else if (dt == 2) val = o[2][qt];
        else              val = o[3][qt];
        float* mg = &Mg[(qt * 16 + ql) * 66 + dt * 16 + quad * 4];
        if (st) {
          f32x4 old = *(const f32x4*)mg;
          val = val + old;
        }
        *(f32x4*)mg = val;
      }
    }
    __syncthreads();
    // write partial O (bf16) + l to global
    int q = tid >> 2, ds = (tid & 3) * 16;
    size_t base = (((size_t)c * 16 + bh) * 16 + j) * 2 + t01;
    if ((tid & 3) == 0)
      Ml[base * 64 + q] = Lg[0][q] + Lg[1][q] + Lg[2][q] + Lg[3][q];
    const float* mrow = &Mg[q * 66 + ds];
    union { bf16x8 v; u16 e[8]; } o0, o1;
#pragma unroll
    for (int i = 0; i < 8; ++i) {
      o0.e[i] = f2bf(mrow[i]);
      o1.e[i] = f2bf(mrow[i + 8]);
    }
    u16* pp = Pp + base * 4096 + q * 64 + ds;
    *(bf16x8*)pp = o0.v;
    *(bf16x8*)(pp + 8) = o1.v;
    __syncthreads();   // Mg/Lg safe to reuse
  };

  // prologue
  int i0 = c * 11;
  int kb0 = (i0 <= j) ? i0 : (i0 - j - 1);
  stage(0, kb0 * 64);
  loadQ(rsw > 0 ? tileA : tileB);
  zeroAcc();

  for (int r = 0; r < 11; ++r) {
    int cur = r & 1;
    __syncthreads();   // staging of cur drained
    if (r == rsw && r > 0) {   // phase switch A -> B (rsw in 1..10)
      flush(0);
      loadQ(tileB);
      zeroAcc();
    }
    if (r < 10) {
      int i1 = c * 11 + r + 1;
      int kb = (i1 <= j) ? i1 : (i1 - j - 1);
      stage(cur ^ 1, kb * 64);
    }
    int i = c * 11 + r;
    int kb = (i <= j) ? i : (i - j - 1);
    int tile = (r < rsw) ? tileA : tileB;
    process(cur, kb == tile);
  }
  flush(rsw >= 11 ? 0 : 1);
  // zero l for phases this chunk never ran (merge kernel skips l==0)
  size_t mb = ((((size_t)c * 16 + bh) * 16 + j) * 2) * 64;
  if (rsw <= 0 && tid < 64) Ml[mb + tid] = 0.0f;
  if (rsw >= 11 && tid < 64) Ml[mb + 64 + tid] = 0.0f;
}

// ---------------- merge <=3 chunk partial sums per row -> Ob ----------------
__global__ __launch_bounds__(256) void attn_merge(
    const u16* __restrict__ Pp, const float* __restrict__ Ml,
    u16* __restrict__ Ob) {
  int tid = threadIdx.x;
  int j = blockIdx.x, t = blockIdx.y, bh = blockIdx.z;
  int q = tid >> 2, ds = (tid & 3) * 16;
  float lc[3], L = 0.0f;
#pragma unroll
  for (int c = 0; c < 3; ++c) {
    lc[c] = Ml[((((size_t)c * 16 + bh) * 16 + j) * 2 + t) * 64 + q];
    L += lc[c];
  }
  float O[16];
#pragma unroll
  for (int i = 0; i < 16; ++i) O[i] = 0.0f;
#pragma unroll
  for (int c = 0; c < 3; ++c) {
    if (lc[c] > 0.0f) {
      size_t pb = ((((size_t)c * 16 + bh) * 16 + j) * 2 + t) * 4096 + q * 64 + ds;
      union { bf16x8 v; u16 e[8]; } a, b;
      a.v = *(const bf16x8*)(Pp + pb);
      b.v = *(const bf16x8*)(Pp + pb + 8);
#pragma unroll
      for (int i = 0; i < 8; ++i) {
        O[i]     += bf2f(a.e[i]);
        O[i + 8] += bf2f(b.e[i]);
      }
    }
  }
  float inv = 1.0f / L;
  int tile_abs = t ? (31 - j) : j;
  int s = tile_abs * 64 + q;
  int b2 = bh >> 3, h = bh & 7;
  size_t row = ((size_t)(b2 * 2048 + s)) * 512 + h * 64 + ds;
  union { bf16x8 v; u16 e[8]; } o0, o1;
#pragma unroll
  for (int i = 0; i < 8; ++i) {
    o0.e[i] = f2bf(O[i] * inv);
    o1.e[i] = f2bf(O[i + 8] * inv);
  }
  *(bf16x8*)(Ob + row)     = o0.v;
  *(bf16x8*)(Ob + row + 8) = o1.v;
}

// ---------------- out_proj GEMM: out = O @ w_out^T + b_out (fp32 out) ----------------
__global__ __launch_bounds__(256) void outproj_gemm(
    const u16* __restrict__ Ob, const u16* __restrict__ wb,
    const float* __restrict__ bout, float* __restrict__ out) {
  const int K = 512;
  __shared__ u16 At[2][64 * 32];
  __shared__ u16 Bt[2][128 * 32];
  int tid = threadIdx.x;
  int w = tid >> 6, lane = tid & 63;
  int ql = lane & 15, quad = lane >> 4;
  int wr = w >> 1, wc = w & 1;
  int mtile = blockIdx.x * 64, ntile = blockIdx.y * 128;

  int r4 = lane >> 2, c4 = lane & 3;
  int swz4 = c4 ^ (r4 & 3);

  const u16* ag0 = Ob + (size_t)(mtile + w * 16 + r4) * K + swz4 * 8;
  const u16* bg0 = wb + (size_t)(ntile + w * 32 + r4) * K + swz4 * 8;

  f32x4 acc[2][4];
#pragma unroll
  for (int t = 0; t < 2; ++t)
#pragma unroll
    for (int u = 0; u < 4; ++u) acc[t][u] = (f32x4){0, 0, 0, 0};

  lds_cp16(&At[0][w * 512], ag0);
  lds_cp16(&Bt[0][w * 1024], bg0);
  lds_cp16(&Bt[0][w * 1024 + 512], bg0 + 16 * K);

  int cb = ql & 3;
  for (int kk = 0; kk < 16; ++kk) {
    int cur = kk & 1;
    __syncthreads();
    if (kk < 15) {
      int k0 = (kk + 1) * 32;
      lds_cp16(&At[cur ^ 1][w * 512], ag0 + k0);
      lds_cp16(&Bt[cur ^ 1][w * 1024], bg0 + k0);
      lds_cp16(&Bt[cur ^ 1][w * 1024 + 512], bg0 + 16 * K + k0);
    }
    bf16x8 af[2], bf[4];
#pragma unroll
    for (int t = 0; t < 2; ++t) {
      int row = wr * 32 + t * 16 + ql;
      af[t] = *(const bf16x8*)(&At[cur][row * 32 + ((quad ^ cb) * 8)]);
    }
#pragma unroll
    for (int u = 0; u < 4; ++u) {
      int row = wc * 64 + u * 16 + ql;
      bf[u] = *(const bf16x8*)(&Bt[cur][row * 32 + ((quad ^ cb) * 8)]);
    }
#pragma unroll
    for (int t = 0; t < 2; ++t)
#pragma unroll
      for (int u = 0; u < 4; ++u)
        acc[t][u] = __builtin_amdgcn_mfma_f32_16x16x32_bf16(af[t], bf[u], acc[t][u], 0, 0, 0);
  }

#pragma unroll
  for (int u = 0; u < 4; ++u) {
    int n = ntile + wc * 64 + u * 16 + ql;
    float bias = bout[n];
#pragma unroll
    for (int t = 0; t < 2; ++t)
#pragma unroll
      for (int r = 0; r < 4; ++r) {
        int mm = mtile + wr * 32 + t * 16 + quad * 4 + r;
        out[(size_t)mm * 512 + n] = acc[t][u][r] + bias;
      }
  }
}

extern "C" void kernel_launch(void* const* d_in, const int* in_sizes, int n_in,
                              void* d_out, int out_size, void* d_ws, size_t ws_size,
                              hipStream_t stream) {
  const float* x     = (const float*)d_in[0];  // [2,2048,512]
  const float* w_in  = (const float*)d_in[1];  // [1536,512]
  const float* b_in  = (const float*)d_in[2];  // [1536]
  const float* w_out = (const float*)d_in[3];  // [512,512]
  const float* b_out = (const float*)d_in[4];  // [512]
  float* out = (float*)d_out;                  // [2,2048,512] fp32
  char* ws = (char*)d_ws;

  u16* xb    = (u16*)(ws);             // 4096x512 bf16   (4 MB)
  u16* winb  = (u16*)(ws + 4194304);   // 1536x512 bf16   (1.5 MB)
  u16* woutb = (u16*)(ws + 5767168);   // 512x512 bf16    (0.5 MB)
  u16* Qb    = (u16*)(ws + 6291456);   // [16][2048][64]  (4 MB)
  u16* Kb    = (u16*)(ws + 10485760);  // [16][2048][64]  (4 MB)
  u16* Vt    = (u16*)(ws + 14680064);  // [16][64][2048]  (4 MB)
  u16* Ob    = (u16*)(ws + 18874368);  // [4096][512]     (4 MB)
  u16* Pp    = (u16*)(ws + 23068672);  // [3][16][16][2][64][64] bf16 (12.6 MB)
  float* Ml  = (float*)(ws + 35651584); // [3][16][16][2][64] f32 (393 KB)

  cvt_all<<<3072, 256, 0, stream>>>((const float4*)x, (const float4*)w_in,
                                    (const float4*)w_out, xb, winb, woutb);
  inproj_gemm<<<dim3(32, 12), 256, 0, stream>>>(xb, winb, b_in, Qb, Kb, Vt);
  attn_kernel<<<dim3(16, 3, 16), 256, 0, stream>>>(Qb, Kb, Vt, Pp, Ml);
  attn_merge<<<dim3(16, 2, 16), 256, 0, stream>>>(Pp, Ml, Ob);
  outproj_gemm<<<dim3(64, 4), 256, 0, stream>>>(Ob, woutb, b_out, out);
}

// Round 11
// 134.696 us; speedup vs baseline: 1.8211x; 1.8211x over previous
//
#include <hip/hip_runtime.h>
#include <hip/hip_bf16.h>

typedef unsigned short u16;
typedef unsigned int u32;
typedef __attribute__((ext_vector_type(8))) short bf16x8;  // 8 bf16 (4 VGPRs)
typedef __attribute__((ext_vector_type(4))) short bf16x4;  // 4 bf16 (2 VGPRs)
typedef __attribute__((ext_vector_type(4))) float f32x4;

#define DEVI __device__ __forceinline__

DEVI u16 f2bf(float f) {
  union { float f; unsigned int u; } v; v.f = f;
  unsigned int u = v.u;
  unsigned int r = (u + 0x7fffu + ((u >> 16) & 1u)) >> 16;  // RNE
  return (u16)r;
}

DEVI float bf2f(u16 b) {
  union { unsigned int u; float f; } v; v.u = ((unsigned int)b) << 16;
  return v.f;
}

DEVI float fexp2(float x) {
#if __has_builtin(__builtin_amdgcn_exp2f)
  return __builtin_amdgcn_exp2f(x);
#else
  return exp2f(x);
#endif
}

// pack two fp32 -> two bf16 (round +half) in one u32: b -> low16, a -> high16
DEVI u32 pkbf(float a, float b) {
  union { float f; u32 u; } ua, ub;
  ua.f = a; ub.f = b;
  return __builtin_amdgcn_perm(ua.u + 0x8000u, ub.u + 0x8000u, 0x07060302u);
}

// async global->LDS, 16B per lane; LDS dest = uniform base + lane*16
DEVI void lds_cp16(u16* lds, const u16* g) {
  __builtin_amdgcn_global_load_lds(
      (const __attribute__((address_space(1))) u32*)g,
      (__attribute__((address_space(3))) u32*)lds, 16, 0, 0);
}

DEVI f32x4 mfma16x16x16_bf16(bf16x4 a, bf16x4 b, f32x4 c) {
#if __has_builtin(__builtin_amdgcn_mfma_f32_16x16x16bf16_1k)
  return __builtin_amdgcn_mfma_f32_16x16x16bf16_1k(a, b, c, 0, 0, 0);
#else
  f32x4 d;
  asm volatile("v_mfma_f32_16x16x16_bf16 %0, %1, %2, %3"
               : "=v"(d) : "v"(a), "v"(b), "v"(c));
  return d;
#endif
}

// ---------------- fp32 -> bf16 conversion (x, w_in, w_out merged) ----------------
__global__ __launch_bounds__(256) void cvt_all(
    const float4* __restrict__ x, const float4* __restrict__ wi,
    const float4* __restrict__ wo, u16* __restrict__ xb,
    u16* __restrict__ wib, u16* __restrict__ wob) {
  int i = blockIdx.x * 256 + threadIdx.x;
  const float4* src; u16* dst; int off;
  if (i < 524288)      { src = x;  dst = xb;  off = i; }
  else if (i < 720896) { src = wi; dst = wib; off = i - 524288; }
  else                 { src = wo; dst = wob; off = i - 720896; }
  float4 f = src[off];
  ushort4 o;
  o.x = f2bf(f.x); o.y = f2bf(f.y); o.z = f2bf(f.z); o.w = f2bf(f.w);
  ((ushort4*)dst)[off] = o;
}

// ---------------- in_proj GEMM: qvk = x @ w_in^T + b_in (R3-proven config) ----------------
// Q is PRE-SCALED by (1/sqrt(64))*log2(e) so attention scores come out in
// exp2 domain with no per-score multiply.
__global__ __launch_bounds__(256) void inproj_gemm(
    const u16* __restrict__ xb, const u16* __restrict__ wb,
    const float* __restrict__ bin,
    u16* __restrict__ Qb, u16* __restrict__ Kb, u16* __restrict__ Vt) {
  const int K = 512;
  const float SCL = 0.180336878f;  // (1/sqrt(64)) * log2(e)
  __shared__ u16 At[2][128 * 32];
  __shared__ u16 Bt[2][128 * 32];
  int tid = threadIdx.x;
  int w = tid >> 6, lane = tid & 63;
  int ql = lane & 15, quad = lane >> 4;
  int wr = w >> 1, wc = w & 1;
  int mtile = blockIdx.x * 128, ntile = blockIdx.y * 128;

  int r4 = lane >> 2, c4 = lane & 3;
  int swz4 = c4 ^ (r4 & 3);

  const u16* ag0 = xb + (size_t)(mtile + w * 32 + r4) * K + swz4 * 8;
  const u16* bg0 = wb + (size_t)(ntile + w * 32 + r4) * K + swz4 * 8;

  f32x4 acc[4][4];
#pragma unroll
  for (int t = 0; t < 4; ++t)
#pragma unroll
    for (int u = 0; u < 4; ++u) acc[t][u] = (f32x4){0, 0, 0, 0};

  lds_cp16(&At[0][w * 1024], ag0);
  lds_cp16(&At[0][w * 1024 + 512], ag0 + 16 * K);
  lds_cp16(&Bt[0][w * 1024], bg0);
  lds_cp16(&Bt[0][w * 1024 + 512], bg0 + 16 * K);

  int cb = ql & 3;
  for (int kk = 0; kk < 16; ++kk) {
    int cur = kk & 1;
    __syncthreads();
    if (kk < 15) {
      int k0 = (kk + 1) * 32;
      lds_cp16(&At[cur ^ 1][w * 1024], ag0 + k0);
      lds_cp16(&At[cur ^ 1][w * 1024 + 512], ag0 + 16 * K + k0);
      lds_cp16(&Bt[cur ^ 1][w * 1024], bg0 + k0);
      lds_cp16(&Bt[cur ^ 1][w * 1024 + 512], bg0 + 16 * K + k0);
    }
    bf16x8 af[4], bf[4];
#pragma unroll
    for (int t = 0; t < 4; ++t) {
      int row = wr * 64 + t * 16 + ql;
      af[t] = *(const bf16x8*)(&At[cur][row * 32 + ((quad ^ cb) * 8)]);
    }
#pragma unroll
    for (int u = 0; u < 4; ++u) {
      int row = wc * 64 + u * 16 + ql;
      bf[u] = *(const bf16x8*)(&Bt[cur][row * 32 + ((quad ^ cb) * 8)]);
    }
#pragma unroll
    for (int t = 0; t < 4; ++t)
#pragma unroll
      for (int u = 0; u < 4; ++u)
        acc[t][u] = __builtin_amdgcn_mfma_f32_16x16x32_bf16(af[t], bf[u], acc[t][u], 0, 0, 0);
  }

#pragma unroll
  for (int u = 0; u < 4; ++u) {
    int n = ntile + wc * 64 + u * 16 + ql;
    float bias = bin[n];
    int chunk = n >> 9;       // 0=q, 1=v, 2=k
    int nc = n & 511;
    int h = nc >> 6, d = nc & 63;
#pragma unroll
    for (int t = 0; t < 4; ++t)
#pragma unroll
      for (int r = 0; r < 4; ++r) {
        int m = mtile + wr * 64 + t * 16 + quad * 4 + r;
        int b = m >> 11, s = m & 2047;
        float v = acc[t][u][r] + bias;
        int bh = b * 8 + h;
        if (chunk == 0)      Qb[((size_t)bh * 2048 + s) * 64 + d] = f2bf(v * SCL);
        else if (chunk == 2) Kb[((size_t)bh * 2048 + s) * 64 + d] = f2bf(v);
        else                 Vt[((size_t)bh * 64 + d) * 2048 + s] = f2bf(v);
      }
  }
}

// ---------------- flash attention (causal): FIXED-MAX softmax, 5-chunk split ----------------
// R8-proven structure, chunk count 3 -> 5 for occupancy: 32 KB LDS + ~88 VGPR
// allow 5 WGs/CU; grid (16,5,16) = 1280 WGs = exactly 5/CU = 20 waves/CU.
// Pair j = tiles A=j, B=31-j: 33 items; chunk c takes items c*7 .. c*7+6
// (i<33 real; chunk 4 has 2 dummy rounds, wave-uniform guard). Fixed-max
// exp2 softmax (Q pre-scaled): no m, no rescale, no per-item cross-lane
// reductions. Partial sums (O^T bf16, l) written per chunk; l==0 marks
// "never touched" (registers init 0). attn_merge adds <=5 partials.
__global__ __launch_bounds__(256) void attn_kernel(
    const u16* __restrict__ Qb, const u16* __restrict__ Kb,
    const u16* __restrict__ Vt, u16* __restrict__ Pp, float* __restrict__ Ml) {
  const int S = 2048;
  __shared__ u16 Kt[2][4096];   // [buf][64 keys x 64 dh], 16B chunks swizzled
  __shared__ u16 Vl[2][4096];   // [buf][64 dh x 64 keys]
  int tid = threadIdx.x;
  int w = tid >> 6, lane = tid & 63;
  int ql = lane & 15, quad = lane >> 4;
  int j = blockIdx.x;          // pair 0..15
  int c = blockIdx.y;          // chunk 0..4
  int bh = blockIdx.z;
  int tileA = j, tileB = 31 - j;
  int qbaseA = tileA * 64 + w * 16;
  int qbaseB = tileB * 64 + w * 16;
  const u16* Qh = Qb + (size_t)bh * S * 64;
  const u16* Kh = Kb + (size_t)bh * S * 64;
  const u16* Vh = Vt + (size_t)bh * 64 * S;

  int r8 = lane >> 3, c8 = lane & 7;
  int swz = c8 ^ r8;
  int cb = ql & 7;

  bf16x8 qA0 = *(const bf16x8*)(Qh + (size_t)(qbaseA + ql) * 64 + quad * 8);
  bf16x8 qA1 = *(const bf16x8*)(Qh + (size_t)(qbaseA + ql) * 64 + 32 + quad * 8);
  bf16x8 qB0 = *(const bf16x8*)(Qh + (size_t)(qbaseB + ql) * 64 + quad * 8);
  bf16x8 qB1 = *(const bf16x8*)(Qh + (size_t)(qbaseB + ql) * 64 + 32 + quad * 8);

  f32x4 oA[4] = {{0,0,0,0},{0,0,0,0},{0,0,0,0},{0,0,0,0}};
  f32x4 oB[4] = {{0,0,0,0},{0,0,0,0},{0,0,0,0},{0,0,0,0}};
  float lA = 0.0f, lB = 0.0f;

  // item i (0..32): i <= j -> (tile A, kb=i); else (tile B, kb=i-j-1)
  auto kbOf = [&](int i) { return (i <= j) ? i : (i - j - 1); };
  auto stage = [&](int buf, int kbase) {
    const u16* kg = Kh + (size_t)(kbase + w * 16 + r8) * 64 + swz * 8;
    lds_cp16(&Kt[buf][w * 1024], kg);
    lds_cp16(&Kt[buf][w * 1024 + 512], kg + 8 * 64);
    const u16* vg = Vh + (size_t)(w * 16 + r8) * S + kbase + swz * 8;
    lds_cp16(&Vl[buf][w * 1024], vg);
    lds_cp16(&Vl[buf][w * 1024 + 512], vg + 8 * S);
  };
  auto process = [&](int cur, int kbase, int qbase, bf16x8 x0, bf16x8 x1,
                     f32x4 (&o)[4], float& l) {
    int q = qbase + ql;
    f32x4 st[4];
#pragma unroll
    for (int t = 0; t < 4; ++t) {
      const u16* kr = &Kt[cur][(t * 16 + ql) * 64];
      bf16x8 kf0 = *(const bf16x8*)(kr + ((quad ^ cb) * 8));
      bf16x8 kf1 = *(const bf16x8*)(kr + (((quad + 4) ^ cb) * 8));
      f32x4 s = {0, 0, 0, 0};
      s = __builtin_amdgcn_mfma_f32_16x16x32_bf16(kf0, x0, s, 0, 0, 0);
      s = __builtin_amdgcn_mfma_f32_16x16x32_bf16(kf1, x1, s, 0, 0, 0);
      st[t] = s;
    }
    bool needmask = (kbase + 63 > qbase);
    float e[4][4];
#pragma unroll
    for (int t = 0; t < 4; ++t)
#pragma unroll
      for (int r = 0; r < 4; ++r) {
        float v = st[t][r];
        if (needmask) {
          int key = kbase + t * 16 + quad * 4 + r;
          if (key > q) v = -3.0e38f;   // exp2 -> 0
        }
        e[t][r] = fexp2(v);
      }
    // l accumulate, tree (no cross-lane here!)
    float s0 = (e[0][0] + e[0][1]) + (e[0][2] + e[0][3]);
    float s1 = (e[1][0] + e[1][1]) + (e[1][2] + e[1][3]);
    float s2 = (e[2][0] + e[2][1]) + (e[2][2] + e[2][3]);
    float s3 = (e[3][0] + e[3][1]) + (e[3][2] + e[3][3]);
    l += (s0 + s1) + (s2 + s3);
    // pack P^T (bf16) via v_perm
    bf16x4 p[4];
#pragma unroll
    for (int t = 0; t < 4; ++t) {
      union { bf16x4 v; u32 u[2]; } pk;
      pk.u[0] = pkbf(e[t][1], e[t][0]);
      pk.u[1] = pkbf(e[t][3], e[t][2]);
      p[t] = pk.v;
    }
    // O^T += V^T x P^T
#pragma unroll
    for (int t = 0; t < 4; ++t)
#pragma unroll
      for (int d = 0; d < 4; ++d) {
        const u16* vr = &Vl[cur][(d * 16 + ql) * 64];
        bf16x4 vf = *(const bf16x4*)(vr + (((t * 2 + (quad >> 1)) ^ cb) * 8 + (quad & 1) * 4));
        o[d] = mfma16x16x16_bf16(vf, p[t], o[d]);
      }
  };

  stage(0, kbOf(c * 7) * 64);   // prologue (c*7 <= 28 always real)

  for (int r = 0; r < 7; ++r) {
    int i = c * 7 + r;
    int cur = r & 1;
    __syncthreads();   // staging of cur drained
    if (r < 6) {
      int i1 = i + 1;
      if (i1 < 33) stage(cur ^ 1, kbOf(i1) * 64);
    }
    if (i < 33) {
      if (i <= j) process(cur, i * 64, qbaseA, qA0, qA1, oA, lA);
      else        process(cur, (i - j - 1) * 64, qbaseB, qB0, qB1, oB, lB);
    }
  }

  // --- epilogue: raw partial sums. P[c][bh][j][tile][q 64][d 64] bf16;
  //     Ml[c][bh][j][tile][q 64] f32 (l reduced across quads once) ---
  lA += __shfl_xor(lA, 16); lA += __shfl_xor(lA, 32);
  lB += __shfl_xor(lB, 16); lB += __shfl_xor(lB, 32);
  int qrow = w * 16 + ql;
  size_t pb = ((((size_t)c * 16 + bh) * 16 + j) * 2) * 4096;
  size_t mb = ((((size_t)c * 16 + bh) * 16 + j) * 2) * 64;
  if (quad == 0) {
    Ml[mb + qrow]      = lA;   // 0.0 if this chunk never touched tile A
    Ml[mb + 64 + qrow] = lB;
  }
  bool validA = (c * 7 <= j);        // chunk contains any tile-A item
  bool validB = (c * 7 + 6 > j);     // chunk contains any tile-B item
  if (validA) {
#pragma unroll
    for (int dt = 0; dt < 4; ++dt) {
      ushort4 v;
      v.x = f2bf(oA[dt][0]); v.y = f2bf(oA[dt][1]);
      v.z = f2bf(oA[dt][2]); v.w = f2bf(oA[dt][3]);
      *(ushort4*)(Pp + pb + qrow * 64 + dt * 16 + quad * 4) = v;
    }
  }
  if (validB) {
#pragma unroll
    for (int dt = 0; dt < 4; ++dt) {
      ushort4 v;
      v.x = f2bf(oB[dt][0]); v.y = f2bf(oB[dt][1]);
      v.z = f2bf(oB[dt][2]); v.w = f2bf(oB[dt][3]);
      *(ushort4*)(Pp + pb + 4096 + qrow * 64 + dt * 16 + quad * 4) = v;
    }
  }
}

// ---------------- merge <=5 chunk partial sums per row -> Ob ----------------
__global__ __launch_bounds__(256) void attn_merge(
    const u16* __restrict__ Pp, const float* __restrict__ Ml,
    u16* __restrict__ Ob) {
  int tid = threadIdx.x;
  int j = blockIdx.x, t = blockIdx.y, bh = blockIdx.z;
  int q = tid >> 2, ds = (tid & 3) * 16;
  float lc[5], L = 0.0f;
#pragma unroll
  for (int c = 0; c < 5; ++c) {
    lc[c] = Ml[((((size_t)c * 16 + bh) * 16 + j) * 2 + t) * 64 + q];
    L += lc[c];
  }
  float O[16];
#pragma unroll
  for (int i = 0; i < 16; ++i) O[i] = 0.0f;
#pragma unroll
  for (int c = 0; c < 5; ++c) {
    if (lc[c] > 0.0f) {
      size_t pb = ((((size_t)c * 16 + bh) * 16 + j) * 2 + t) * 4096 + q * 64 + ds;
      union { bf16x8 v; u16 e[8]; } a, b;
      a.v = *(const bf16x8*)(Pp + pb);
      b.v = *(const bf16x8*)(Pp + pb + 8);
#pragma unroll
      for (int i = 0; i < 8; ++i) {
        O[i]     += bf2f(a.e[i]);
        O[i + 8] += bf2f(b.e[i]);
      }
    }
  }
  float inv = 1.0f / L;
  int tile_abs = t ? (31 - j) : j;
  int s = tile_abs * 64 + q;
  int b2 = bh >> 3, h = bh & 7;
  size_t row = ((size_t)(b2 * 2048 + s)) * 512 + h * 64 + ds;
  union { bf16x8 v; u16 e[8]; } o0, o1;
#pragma unroll
  for (int i = 0; i < 8; ++i) {
    o0.e[i] = f2bf(O[i] * inv);
    o1.e[i] = f2bf(O[i + 8] * inv);
  }
  *(bf16x8*)(Ob + row)     = o0.v;
  *(bf16x8*)(Ob + row + 8) = o1.v;
}

// ---------------- out_proj GEMM: out = O @ w_out^T + b_out (fp32 out) ----------------
__global__ __launch_bounds__(256) void outproj_gemm(
    const u16* __restrict__ Ob, const u16* __restrict__ wb,
    const float* __restrict__ bout, float* __restrict__ out) {
  const int K = 512;
  __shared__ u16 At[2][64 * 32];
  __shared__ u16 Bt[2][128 * 32];
  int tid = threadIdx.x;
  int w = tid >> 6, lane = tid & 63;
  int ql = lane & 15, quad = lane >> 4;
  int wr = w >> 1, wc = w & 1;
  int mtile = blockIdx.x * 64, ntile = blockIdx.y * 128;

  int r4 = lane >> 2, c4 = lane & 3;
  int swz4 = c4 ^ (r4 & 3);

  const u16* ag0 = Ob + (size_t)(mtile + w * 16 + r4) * K + swz4 * 8;
  const u16* bg0 = wb + (size_t)(ntile + w * 32 + r4) * K + swz4 * 8;

  f32x4 acc[2][4];
#pragma unroll
  for (int t = 0; t < 2; ++t)
#pragma unroll
    for (int u = 0; u < 4; ++u) acc[t][u] = (f32x4){0, 0, 0, 0};

  lds_cp16(&At[0][w * 512], ag0);
  lds_cp16(&Bt[0][w * 1024], bg0);
  lds_cp16(&Bt[0][w * 1024 + 512], bg0 + 16 * K);

  int cb = ql & 3;
  for (int kk = 0; kk < 16; ++kk) {
    int cur = kk & 1;
    __syncthreads();
    if (kk < 15) {
      int k0 = (kk + 1) * 32;
      lds_cp16(&At[cur ^ 1][w * 512], ag0 + k0);
      lds_cp16(&Bt[cur ^ 1][w * 1024], bg0 + k0);
      lds_cp16(&Bt[cur ^ 1][w * 1024 + 512], bg0 + 16 * K + k0);
    }
    bf16x8 af[2], bf[4];
#pragma unroll
    for (int t = 0; t < 2; ++t) {
      int row = wr * 32 + t * 16 + ql;
      af[t] = *(const bf16x8*)(&At[cur][row * 32 + ((quad ^ cb) * 8)]);
    }
#pragma unroll
    for (int u = 0; u < 4; ++u) {
      int row = wc * 64 + u * 16 + ql;
      bf[u] = *(const bf16x8*)(&Bt[cur][row * 32 + ((quad ^ cb) * 8)]);
    }
#pragma unroll
    for (int t = 0; t < 2; ++t)
#pragma unroll
      for (int u = 0; u < 4; ++u)
        acc[t][u] = __builtin_amdgcn_mfma_f32_16x16x32_bf16(af[t], bf[u], acc[t][u], 0, 0, 0);
  }

#pragma unroll
  for (int u = 0; u < 4; ++u) {
    int n = ntile + wc * 64 + u * 16 + ql;
    float bias = bout[n];
#pragma unroll
    for (int t = 0; t < 2; ++t)
#pragma unroll
      for (int r = 0; r < 4; ++r) {
        int mm = mtile + wr * 32 + t * 16 + quad * 4 + r;
        out[(size_t)mm * 512 + n] = acc[t][u][r] + bias;
      }
  }
}

extern "C" void kernel_launch(void* const* d_in, const int* in_sizes, int n_in,
                              void* d_out, int out_size, void* d_ws, size_t ws_size,
                              hipStream_t stream) {
  const float* x     = (const float*)d_in[0];  // [2,2048,512]
  const float* w_in  = (const float*)d_in[1];  // [1536,512]
  const float* b_in  = (const float*)d_in[2];  // [1536]
  const float* w_out = (const float*)d_in[3];  // [512,512]
  const float* b_out = (const float*)d_in[4];  // [512]
  float* out = (float*)d_out;                  // [2,2048,512] fp32
  char* ws = (char*)d_ws;

  u16* xb    = (u16*)(ws);             // 4096x512 bf16   (4 MB)
  u16* winb  = (u16*)(ws + 4194304);   // 1536x512 bf16   (1.5 MB)
  u16* woutb = (u16*)(ws + 5767168);   // 512x512 bf16    (0.5 MB)
  u16* Qb    = (u16*)(ws + 6291456);   // [16][2048][64]  (4 MB)
  u16* Kb    = (u16*)(ws + 10485760);  // [16][2048][64]  (4 MB)
  u16* Vt    = (u16*)(ws + 14680064);  // [16][64][2048]  (4 MB)
  u16* Ob    = (u16*)(ws + 18874368);  // [4096][512]     (4 MB)
  u16* Pp    = (u16*)(ws + 23068672);  // [5][16][16][2][64][64] bf16 (21 MB)
  float* Ml  = (float*)(ws + 44040192); // [5][16][16][2][64] f32 (655 KB)

  cvt_all<<<3072, 256, 0, stream>>>((const float4*)x, (const float4*)w_in,
                                    (const float4*)w_out, xb, winb, woutb);
  inproj_gemm<<<dim3(32, 12), 256, 0, stream>>>(xb, winb, b_in, Qb, Kb, Vt);
  attn_kernel<<<dim3(16, 5, 16), 256, 0, stream>>>(Qb, Kb, Vt, Pp, Ml);
  attn_merge<<<dim3(16, 2, 16), 256, 0, stream>>>(Pp, Ml, Ob);
  outproj_gemm<<<dim3(64, 4), 256, 0, stream>>>(Ob, woutb, b_out, out);
}

// Round 13
// 124.386 us; speedup vs baseline: 1.9721x; 1.0829x over previous
//
#include <hip/hip_runtime.h>
#include <hip/hip_bf16.h>

typedef unsigned short u16;
typedef unsigned int u32;
typedef __attribute__((ext_vector_type(8))) short bf16x8;  // 8 bf16 (4 VGPRs)
typedef __attribute__((ext_vector_type(4))) short bf16x4;  // 4 bf16 (2 VGPRs)
typedef __attribute__((ext_vector_type(4))) float f32x4;

#define DEVI __device__ __forceinline__

DEVI u16 f2bf(float f) {
  union { float f; unsigned int u; } v; v.f = f;
  unsigned int u = v.u;
  unsigned int r = (u + 0x7fffu + ((u >> 16) & 1u)) >> 16;  // RNE
  return (u16)r;
}

DEVI float bf2f(u16 b) {
  union { unsigned int u; float f; } v; v.u = ((unsigned int)b) << 16;
  return v.f;
}

DEVI float fexp2(float x) {
#if __has_builtin(__builtin_amdgcn_exp2f)
  return __builtin_amdgcn_exp2f(x);
#else
  return exp2f(x);
#endif
}

// pack two fp32 -> two bf16 (round +half) in one u32: b -> low16, a -> high16
DEVI u32 pkbf(float a, float b) {
  union { float f; u32 u; } ua, ub;
  ua.f = a; ub.f = b;
  return __builtin_amdgcn_perm(ua.u + 0x8000u, ub.u + 0x8000u, 0x07060302u);
}

// async global->LDS, 16B per lane; LDS dest = uniform base + lane*16
DEVI void lds_cp16(u16* lds, const u16* g) {
  __builtin_amdgcn_global_load_lds(
      (const __attribute__((address_space(1))) u32*)g,
      (__attribute__((address_space(3))) u32*)lds, 16, 0, 0);
}

DEVI f32x4 mfma16x16x16_bf16(bf16x4 a, bf16x4 b, f32x4 c) {
#if __has_builtin(__builtin_amdgcn_mfma_f32_16x16x16bf16_1k)
  return __builtin_amdgcn_mfma_f32_16x16x16bf16_1k(a, b, c, 0, 0, 0);
#else
  f32x4 d;
  asm volatile("v_mfma_f32_16x16x16_bf16 %0, %1, %2, %3"
               : "=v"(d) : "v"(a), "v"(b), "v"(c));
  return d;
#endif
}

// ---------------- fp32 -> bf16 conversion (x, w_in, w_out merged) ----------------
__global__ __launch_bounds__(256) void cvt_all(
    const float4* __restrict__ x, const float4* __restrict__ wi,
    const float4* __restrict__ wo, u16* __restrict__ xb,
    u16* __restrict__ wib, u16* __restrict__ wob) {
  int i = blockIdx.x * 256 + threadIdx.x;
  const float4* src; u16* dst; int off;
  if (i < 524288)      { src = x;  dst = xb;  off = i; }
  else if (i < 720896) { src = wi; dst = wib; off = i - 524288; }
  else                 { src = wo; dst = wob; off = i - 720896; }
  float4 f = src[off];
  ushort4 o;
  o.x = f2bf(f.x); o.y = f2bf(f.y); o.z = f2bf(f.z); o.w = f2bf(f.w);
  ((ushort4*)dst)[off] = o;
}

// ---------------- in_proj GEMM: qvk = x @ w_in^T + b_in ----------------
// 128x128 tile, BK=32, LDS dbuf (R3-proven K-loop). Q pre-scaled by
// (1/sqrt(64))*log2(e). blockIdx.y 0..3 -> Q, 4..7 -> V, 8..11 -> K.
// Q/K written row-major [bh][s][64]. V-WGs transpose their 128x128 output
// tile through the (dead) 32 KB staging LDS -> coalesced 16-B V^T stores
// (kills the 2-byte stride-4KB scatter).
__global__ __launch_bounds__(256) void inproj_gemm(
    const u16* __restrict__ xb, const u16* __restrict__ wb,
    const float* __restrict__ bin,
    u16* __restrict__ Qb, u16* __restrict__ Kb, u16* __restrict__ Vt) {
  const int K = 512;
  const float SCL = 0.180336878f;  // (1/sqrt(64)) * log2(e)
  __shared__ u16 SMEM[16384];      // 32 KB: At[2][4096] | Bt[2][4096]
  u16 (*At)[4096] = (u16 (*)[4096])(SMEM);
  u16 (*Bt)[4096] = (u16 (*)[4096])(SMEM + 8192);
  int tid = threadIdx.x;
  int w = tid >> 6, lane = tid & 63;
  int ql = lane & 15, quad = lane >> 4;
  int wr = w >> 1, wc = w & 1;
  int mtile = blockIdx.x * 128, ntile = blockIdx.y * 128;

  int r4 = lane >> 2, c4 = lane & 3;
  int swz4 = c4 ^ (r4 & 3);

  const u16* ag0 = xb + (size_t)(mtile + w * 32 + r4) * K + swz4 * 8;
  const u16* bg0 = wb + (size_t)(ntile + w * 32 + r4) * K + swz4 * 8;

  f32x4 acc[4][4];
#pragma unroll
  for (int t = 0; t < 4; ++t)
#pragma unroll
    for (int u = 0; u < 4; ++u) acc[t][u] = (f32x4){0, 0, 0, 0};

  lds_cp16(&At[0][w * 1024], ag0);
  lds_cp16(&At[0][w * 1024 + 512], ag0 + 16 * K);
  lds_cp16(&Bt[0][w * 1024], bg0);
  lds_cp16(&Bt[0][w * 1024 + 512], bg0 + 16 * K);

  int cb = ql & 3;
  for (int kk = 0; kk < 16; ++kk) {
    int cur = kk & 1;
    __syncthreads();
    if (kk < 15) {
      int k0 = (kk + 1) * 32;
      lds_cp16(&At[cur ^ 1][w * 1024], ag0 + k0);
      lds_cp16(&At[cur ^ 1][w * 1024 + 512], ag0 + 16 * K + k0);
      lds_cp16(&Bt[cur ^ 1][w * 1024], bg0 + k0);
      lds_cp16(&Bt[cur ^ 1][w * 1024 + 512], bg0 + 16 * K + k0);
    }
    bf16x8 af[4], bf[4];
#pragma unroll
    for (int t = 0; t < 4; ++t) {
      int row = wr * 64 + t * 16 + ql;
      af[t] = *(const bf16x8*)(&At[cur][row * 32 + ((quad ^ cb) * 8)]);
    }
#pragma unroll
    for (int u = 0; u < 4; ++u) {
      int row = wc * 64 + u * 16 + ql;
      bf[u] = *(const bf16x8*)(&Bt[cur][row * 32 + ((quad ^ cb) * 8)]);
    }
#pragma unroll
    for (int t = 0; t < 4; ++t)
#pragma unroll
      for (int u = 0; u < 4; ++u)
        acc[t][u] = __builtin_amdgcn_mfma_f32_16x16x32_bf16(af[t], bf[u], acc[t][u], 0, 0, 0);
  }

  if (blockIdx.y >= 4 && blockIdx.y < 8) {
    // ---- V chunk: LDS-transpose epilogue -> coalesced V^T stores ----
    __syncthreads();               // staging LDS dead; reuse as T[128][128]
    u16* T = SMEM;                 // addr = d*128 + ((s>>3) ^ (d&15))*8 + (s&7)
#pragma unroll
    for (int u = 0; u < 4; ++u) {
      int d_local = wc * 64 + u * 16 + ql;
      float bias = bin[ntile + d_local];
#pragma unroll
      for (int t = 0; t < 4; ++t) {
        int s_local = wr * 64 + t * 16 + quad * 4;   // r adds 0..3
        union { ushort4 v; u16 e[4]; } pk;
#pragma unroll
        for (int r = 0; r < 4; ++r) pk.e[r] = f2bf(acc[t][u][r] + bias);
        int ch = s_local >> 3;
        int sw = ch ^ (d_local & 15);
        *(ushort4*)(&T[d_local * 128 + sw * 8 + (s_local & 7)]) = pk.v;
      }
    }
    __syncthreads();
    int h0 = (ntile - 512) >> 6;
    int b = mtile >> 11;
    int smb = mtile & 2047;
    int s8 = lane & 15;
#pragma unroll
    for (int i = 0; i < 8; ++i) {
      int d_local = i * 16 + w * 4 + (lane >> 4);
      int sw = s8 ^ (d_local & 15);
      bf16x8 vrow = *(const bf16x8*)(&T[d_local * 128 + sw * 8]);
      int h = h0 + (d_local >> 6);
      int dh = d_local & 63;
      *(bf16x8*)(&Vt[(((size_t)(b * 8 + h)) * 64 + dh) * 2048 + smb + s8 * 8]) = vrow;
    }
  } else {
    // ---- Q / K chunks: row-major stores (chunk 0 = Q, 2 = K) ----
    int chunk = (int)(blockIdx.y >> 2);   // 0 or 2
#pragma unroll
    for (int u = 0; u < 4; ++u) {
      int n = ntile + wc * 64 + u * 16 + ql;
      float bias = bin[n];
      int nc = n & 511;
      int h = nc >> 6, d = nc & 63;
#pragma unroll
      for (int t = 0; t < 4; ++t)
#pragma unroll
        for (int r = 0; r < 4; ++r) {
          int m = mtile + wr * 64 + t * 16 + quad * 4 + r;
          int b = m >> 11, s = m & 2047;
          float v = acc[t][u][r] + bias;
          size_t idx = (((size_t)(b * 8 + h)) * 2048 + s) * 64 + d;
          if (chunk == 0) Qb[idx] = f2bf(v * SCL);
          else            Kb[idx] = f2bf(v);
        }
    }
  }
}

// ---------------- flash attention (causal): FIXED-MAX softmax, 3-chunk split ----------------
// R8-proven. Pair j = tiles A=j, B=31-j: 33 items split 11/11/11 across 3
// chunk-WGs (grid 16x3x16, 256 thr, 32 KB LDS). Fixed-max exp2 softmax (Q
// pre-scaled): no m, no rescale, no per-item cross-lane reductions. Partial
// sums (O^T bf16, l) per chunk; l==0 marks "never touched"; attn_merge adds.
__global__ __launch_bounds__(256) void attn_kernel(
    const u16* __restrict__ Qb, const u16* __restrict__ Kb,
    const u16* __restrict__ Vt, u16* __restrict__ Pp, float* __restrict__ Ml) {
  const int S = 2048;
  __shared__ u16 Kt[2][4096];   // [buf][64 keys x 64 dh], 16B chunks swizzled
  __shared__ u16 Vl[2][4096];   // [buf][64 dh x 64 keys]
  int tid = threadIdx.x;
  int w = tid >> 6, lane = tid & 63;
  int ql = lane & 15, quad = lane >> 4;
  int j = blockIdx.x;          // pair 0..15
  int c = blockIdx.y;          // chunk 0..2
  int bh = blockIdx.z;
  int tileA = j, tileB = 31 - j;
  int qbaseA = tileA * 64 + w * 16;
  int qbaseB = tileB * 64 + w * 16;
  const u16* Qh = Qb + (size_t)bh * S * 64;
  const u16* Kh = Kb + (size_t)bh * S * 64;
  const u16* Vh = Vt + (size_t)bh * 64 * S;

  int r8 = lane >> 3, c8 = lane & 7;
  int swz = c8 ^ r8;
  int cb = ql & 7;

  bf16x8 qA0 = *(const bf16x8*)(Qh + (size_t)(qbaseA + ql) * 64 + quad * 8);
  bf16x8 qA1 = *(const bf16x8*)(Qh + (size_t)(qbaseA + ql) * 64 + 32 + quad * 8);
  bf16x8 qB0 = *(const bf16x8*)(Qh + (size_t)(qbaseB + ql) * 64 + quad * 8);
  bf16x8 qB1 = *(const bf16x8*)(Qh + (size_t)(qbaseB + ql) * 64 + 32 + quad * 8);

  f32x4 oA[4] = {{0,0,0,0},{0,0,0,0},{0,0,0,0},{0,0,0,0}};
  f32x4 oB[4] = {{0,0,0,0},{0,0,0,0},{0,0,0,0},{0,0,0,0}};
  float lA = 0.0f, lB = 0.0f;

  // item i (0..32): i <= j -> (tile A, kb=i); else (tile B, kb=i-j-1)
  auto kbOf = [&](int i) { return (i <= j) ? i : (i - j - 1); };
  auto stage = [&](int buf, int kbase) {
    const u16* kg = Kh + (size_t)(kbase + w * 16 + r8) * 64 + swz * 8;
    lds_cp16(&Kt[buf][w * 1024], kg);
    lds_cp16(&Kt[buf][w * 1024 + 512], kg + 8 * 64);
    const u16* vg = Vh + (size_t)(w * 16 + r8) * S + kbase + swz * 8;
    lds_cp16(&Vl[buf][w * 1024], vg);
    lds_cp16(&Vl[buf][w * 1024 + 512], vg + 8 * S);
  };
  auto process = [&](int cur, int kbase, int qbase, bf16x8 x0, bf16x8 x1,
                     f32x4 (&o)[4], float& l) {
    int q = qbase + ql;
    f32x4 st[4];
#pragma unroll
    for (int t = 0; t < 4; ++t) {
      const u16* kr = &Kt[cur][(t * 16 + ql) * 64];
      bf16x8 kf0 = *(const bf16x8*)(kr + ((quad ^ cb) * 8));
      bf16x8 kf1 = *(const bf16x8*)(kr + (((quad + 4) ^ cb) * 8));
      f32x4 s = {0, 0, 0, 0};
      s = __builtin_amdgcn_mfma_f32_16x16x32_bf16(kf0, x0, s, 0, 0, 0);
      s = __builtin_amdgcn_mfma_f32_16x16x32_bf16(kf1, x1, s, 0, 0, 0);
      st[t] = s;
    }
    bool needmask = (kbase + 63 > qbase);
    float e[4][4];
#pragma unroll
    for (int t = 0; t < 4; ++t)
#pragma unroll
      for (int r = 0; r < 4; ++r) {
        float v = st[t][r];
        if (needmask) {
          int key = kbase + t * 16 + quad * 4 + r;
          if (key > q) v = -3.0e38f;   // exp2 -> 0
        }
        e[t][r] = fexp2(v);
      }
    float s0 = (e[0][0] + e[0][1]) + (e[0][2] + e[0][3]);
    float s1 = (e[1][0] + e[1][1]) + (e[1][2] + e[1][3]);
    float s2 = (e[2][0] + e[2][1]) + (e[2][2] + e[2][3]);
    float s3 = (e[3][0] + e[3][1]) + (e[3][2] + e[3][3]);
    l += (s0 + s1) + (s2 + s3);
    bf16x4 p[4];
#pragma unroll
    for (int t = 0; t < 4; ++t) {
      union { bf16x4 v; u32 u[2]; } pk;
      pk.u[0] = pkbf(e[t][1], e[t][0]);
      pk.u[1] = pkbf(e[t][3], e[t][2]);
      p[t] = pk.v;
    }
#pragma unroll
    for (int t = 0; t < 4; ++t)
#pragma unroll
      for (int d = 0; d < 4; ++d) {
        const u16* vr = &Vl[cur][(d * 16 + ql) * 64];
        bf16x4 vf = *(const bf16x4*)(vr + (((t * 2 + (quad >> 1)) ^ cb) * 8 + (quad & 1) * 4));
        o[d] = mfma16x16x16_bf16(vf, p[t], o[d]);
      }
  };

  stage(0, kbOf(c * 11) * 64);   // prologue

  for (int r = 0; r < 11; ++r) {
    int i = c * 11 + r;
    int cur = r & 1;
    __syncthreads();   // staging of cur drained
    if (r < 10) stage(cur ^ 1, kbOf(i + 1) * 64);
    if (i <= j) process(cur, i * 64, qbaseA, qA0, qA1, oA, lA);
    else        process(cur, (i - j - 1) * 64, qbaseB, qB0, qB1, oB, lB);
  }

  // --- epilogue: raw partial sums. P[c][bh][j][tile][q 64][d 64] bf16;
  //     Ml[c][bh][j][tile][q 64] f32 ---
  lA += __shfl_xor(lA, 16); lA += __shfl_xor(lA, 32);
  lB += __shfl_xor(lB, 16); lB += __shfl_xor(lB, 32);
  int qrow = w * 16 + ql;
  size_t pb = ((((size_t)c * 16 + bh) * 16 + j) * 2) * 4096;
  size_t mb = ((((size_t)c * 16 + bh) * 16 + j) * 2) * 64;
  if (quad == 0) {
    Ml[mb + qrow]      = lA;
    Ml[mb + 64 + qrow] = lB;
  }
  bool validA = (c * 11 <= j);
  bool validB = (c * 11 + 10 > j);
  if (validA) {
#pragma unroll
    for (int dt = 0; dt < 4; ++dt) {
      ushort4 v;
      v.x = f2bf(oA[dt][0]); v.y = f2bf(oA[dt][1]);
      v.z = f2bf(oA[dt][2]); v.w = f2bf(oA[dt][3]);
      *(ushort4*)(Pp + pb + qrow * 64 + dt * 16 + quad * 4) = v;
    }
  }
  if (validB) {
#pragma unroll
    for (int dt = 0; dt < 4; ++dt) {
      ushort4 v;
      v.x = f2bf(oB[dt][0]); v.y = f2bf(oB[dt][1]);
      v.z = f2bf(oB[dt][2]); v.w = f2bf(oB[dt][3]);
      *(ushort4*)(Pp + pb + 4096 + qrow * 64 + dt * 16 + quad * 4) = v;
    }
  }
}

// ---------------- merge <=3 chunk partial sums per row -> Ob ----------------
__global__ __launch_bounds__(256) void attn_merge(
    const u16* __restrict__ Pp, const float* __restrict__ Ml,
    u16* __restrict__ Ob) {
  int tid = threadIdx.x;
  int j = blockIdx.x, t = blockIdx.y, bh = blockIdx.z;
  int q = tid >> 2, ds = (tid & 3) * 16;
  float lc[3], L = 0.0f;
#pragma unroll
  for (int c = 0; c < 3; ++c) {
    lc[c] = Ml[((((size_t)c * 16 + bh) * 16 + j) * 2 + t) * 64 + q];
    L += lc[c];
  }
  float O[16];
#pragma unroll
  for (int i = 0; i < 16; ++i) O[i] = 0.0f;
#pragma unroll
  for (int c = 0; c < 3; ++c) {
    if (lc[c] > 0.0f) {
      size_t pb = ((((size_t)c * 16 + bh) * 16 + j) * 2 + t) * 4096 + q * 64 + ds;
      union { bf16x8 v; u16 e[8]; } a, b;
      a.v = *(const bf16x8*)(Pp + pb);
      b.v = *(const bf16x8*)(Pp + pb + 8);
#pragma unroll
      for (int i = 0; i < 8; ++i) {
        O[i]     += bf2f(a.e[i]);
        O[i + 8] += bf2f(b.e[i]);
      }
    }
  }
  float inv = 1.0f / L;
  int tile_abs = t ? (31 - j) : j;
  int s = tile_abs * 64 + q;
  int b2 = bh >> 3, h = bh & 7;
  size_t row = ((size_t)(b2 * 2048 + s)) * 512 + h * 64 + ds;
  union { bf16x8 v; u16 e[8]; } o0, o1;
#pragma unroll
  for (int i = 0; i < 8; ++i) {
    o0.e[i] = f2bf(O[i] * inv);
    o1.e[i] = f2bf(O[i + 8] * inv);
  }
  *(bf16x8*)(Ob + row)     = o0.v;
  *(bf16x8*)(Ob + row + 8) = o1.v;
}

// ---------------- out_proj GEMM: out = O @ w_out^T + b_out (fp32 out) ----------------
__global__ __launch_bounds__(256) void outproj_gemm(
    const u16* __restrict__ Ob, const u16* __restrict__ wb,
    const float* __restrict__ bout, float* __restrict__ out) {
  const int K = 512;
  __shared__ u16 At[2][64 * 32];
  __shared__ u16 Bt[2][128 * 32];
  int tid = threadIdx.x;
  int w = tid >> 6, lane = tid & 63;
  int ql = lane & 15, quad = lane >> 4;
  int wr = w >> 1, wc = w & 1;
  int mtile = blockIdx.x * 64, ntile = blockIdx.y * 128;

  int r4 = lane >> 2, c4 = lane & 3;
  int swz4 = c4 ^ (r4 & 3);

  const u16* ag0 = Ob + (size_t)(mtile + w * 16 + r4) * K + swz4 * 8;
  const u16* bg0 = wb + (size_t)(ntile + w * 32 + r4) * K + swz4 * 8;

  f32x4 acc[2][4];
#pragma unroll
  for (int t = 0; t < 2; ++t)
#pragma unroll
    for (int u = 0; u < 4; ++u) acc[t][u] = (f32x4){0, 0, 0, 0};

  lds_cp16(&At[0][w * 512], ag0);
  lds_cp16(&Bt[0][w * 1024], bg0);
  lds_cp16(&Bt[0][w * 1024 + 512], bg0 + 16 * K);

  int cb = ql & 3;
  for (int kk = 0; kk < 16; ++kk) {
    int cur = kk & 1;
    __syncthreads();
    if (kk < 15) {
      int k0 = (kk + 1) * 32;
      lds_cp16(&At[cur ^ 1][w * 512], ag0 + k0);
      lds_cp16(&Bt[cur ^ 1][w * 1024], bg0 + k0);
      lds_cp16(&Bt[cur ^ 1][w * 1024 + 512], bg0 + 16 * K + k0);
    }
    bf16x8 af[2], bf[4];
#pragma unroll
    for (int t = 0; t < 2; ++t) {
      int row = wr * 32 + t * 16 + ql;
      af[t] = *(const bf16x8*)(&At[cur][row * 32 + ((quad ^ cb) * 8)]);
    }
#pragma unroll
    for (int u = 0; u < 4; ++u) {
      int row = wc * 64 + u * 16 + ql;
      bf[u] = *(const bf16x8*)(&Bt[cur][row * 32 + ((quad ^ cb) * 8)]);
    }
#pragma unroll
    for (int t = 0; t < 2; ++t)
#pragma unroll
      for (int u = 0; u < 4; ++u)
        acc[t][u] = __builtin_amdgcn_mfma_f32_16x16x32_bf16(af[t], bf[u], acc[t][u], 0, 0, 0);
  }

#pragma unroll
  for (int u = 0; u < 4; ++u) {
    int n = ntile + wc * 64 + u * 16 + ql;
    float bias = bout[n];
#pragma unroll
    for (int t = 0; t < 2; ++t)
#pragma unroll
      for (int r = 0; r < 4; ++r) {
        int mm = mtile + wr * 32 + t * 16 + quad * 4 + r;
        out[(size_t)mm * 512 + n] = acc[t][u][r] + bias;
      }
  }
}

extern "C" void kernel_launch(void* const* d_in, const int* in_sizes, int n_in,
                              void* d_out, int out_size, void* d_ws, size_t ws_size,
                              hipStream_t stream) {
  const float* x     = (const float*)d_in[0];  // [2,2048,512]
  const float* w_in  = (const float*)d_in[1];  // [1536,512]
  const float* b_in  = (const float*)d_in[2];  // [1536]
  const float* w_out = (const float*)d_in[3];  // [512,512]
  const float* b_out = (const float*)d_in[4];  // [512]
  float* out = (float*)d_out;                  // [2,2048,512] fp32
  char* ws = (char*)d_ws;

  u16* xb    = (u16*)(ws);             // 4096x512 bf16   (4 MB)
  u16* winb  = (u16*)(ws + 4194304);   // 1536x512 bf16   (1.5 MB)
  u16* woutb = (u16*)(ws + 5767168);   // 512x512 bf16    (0.5 MB)
  u16* Qb    = (u16*)(ws + 6291456);   // [16][2048][64]  (4 MB)
  u16* Kb    = (u16*)(ws + 10485760);  // [16][2048][64]  (4 MB)
  u16* Vt    = (u16*)(ws + 14680064);  // [16][64][2048]  (4 MB)
  u16* Ob    = (u16*)(ws + 18874368);  // [4096][512]     (4 MB)
  u16* Pp    = (u16*)(ws + 23068672);  // [3][16][16][2][64][64] bf16 (12.6 MB)
  float* Ml  = (float*)(ws + 35651584); // [3][16][16][2][64] f32 (393 KB)

  cvt_all<<<3072, 256, 0, stream>>>((const float4*)x, (const float4*)w_in,
                                    (const float4*)w_out, xb, winb, woutb);
  inproj_gemm<<<dim3(32, 12), 256, 0, stream>>>(xb, winb, b_in, Qb, Kb, Vt);
  attn_kernel<<<dim3(16, 3, 16), 256, 0, stream>>>(Qb, Kb, Vt, Pp, Ml);
  attn_merge<<<dim3(16, 2, 16), 256, 0, stream>>>(Pp, Ml, Ob);
  outproj_gemm<<<dim3(64, 4), 256, 0, stream>>>(Ob, woutb, b_out, out);
}